// Round 8
// baseline (328.752 us; speedup 1.0000x reference)
//
#include <hip/hip_runtime.h>

// Problem constants
#define B_  8
#define C_  64
#define O_  64
#define H_  80
#define W_  800
#define NCHM   25          // main kernel: 800/32 exact 32-px chunks

#define ROWS_  10          // staged halo rows: h0-3 .. h0+6 (4 output rows)
#define ROWPX_ 44          // staged cols w0-4 .. w0+39 (quad-aligned)
#define ROWB_  5648u       // 44*128 + 16 pad: rows shift banksets by 1 (write spread)
#define LDSX_BYTES (ROWS_ * 5648)      // 56480 B -> 2 blocks/CU @ 512 thr
#define NTASK  880         // 8 ch-groups * 11 px-quads * 10 rows

typedef short bf16x8 __attribute__((ext_vector_type(8)));
typedef float f32x4  __attribute__((ext_vector_type(4)));

__device__ __forceinline__ unsigned short f2bf(float f) {
    unsigned int u = __float_as_uint(f);
    unsigned int r = u + 0x7FFFu + ((u >> 16) & 1u);   // RNE
    return (unsigned short)(r >> 16);
}

// ---------------------------------------------------------------------------
// Kernel 1: pre-swizzle weight (9,O,C) fp32 into exact A-fragment order, bf16.
// ---------------------------------------------------------------------------
__global__ void k_wfrag(const float* __restrict__ wt, unsigned short* __restrict__ wf) {
    const int t = blockIdx.x * 256 + threadIdx.x;   // < 36864
    const int j    = t & 7;
    const int lane = (t >> 3) & 63;
    const int mt   = (t >> 9) & 3;
    const int ks   = t >> 11;                       // 0..17
    const int tap  = ks >> 1, hf = ks & 1;
    const int o = mt * 16 + (lane & 15);
    const int c = hf * 32 + (lane >> 4) * 8 + j;
    wf[t] = f2bf(wt[(tap * 64 + o) * 64 + c]);
}

// ---------------------------------------------------------------------------
// Kernel 2: FUSED transpose + gather-GEMM, single pass over x.
// Block = 512 thr = 8 waves over (4 h rows) x (2 o-halves); 32-px chunk.
//
// Stage (split-phase, T14): task = (g, q, row), row FASTEST across
// consecutive threads. Phase A issues ALL 16 global float4 loads (2 tasks x
// 8 channels) into registers -> one latency round-trip instead of seven.
// Phase B packs (RNE) and writes one ds_write_b128 per pixel: the full 16-B
// channel-group g of pixel ca+i at
//   lx[row*5648 + (4q+i)*128 + ((g+ca+i)&7)*16]
// ROWB=5648 (not 5632): row advance rotates the bank-set by 1 and row is the
// fastest task index, so a wave's 64 b128 writes spread across all 8
// bank-sets (the b32 pattern of round 4 hit 2 sets -> 11.9M conflicts).
//
// BUGFIX vs rounds 5-7: with the +16 row pad, rowb contributes slot_r*16 to
// address bits 4-6, so the hf "group+=4" XOR must be applied to colb BEFORE
// adding rowb: a = rowb + (colb ^ 64). Applying it after (rounds 5-7) read
// wrong granules (NaN) and could stray past the LDS allocation (crashes).
// colb = slot*128 + swz*16 has bits 4-6 = swz exclusively, so colb^64 is the
// exact group rotation; write and read then share one address formula.
// ---------------------------------------------------------------------------
__global__ void __launch_bounds__(512, 4)
k_main(const float* __restrict__ x,
       const unsigned short* __restrict__ wfrag,
       const float* __restrict__ dh, const float* __restrict__ dw,
       const float* __restrict__ bias, float* __restrict__ out) {
    __shared__ __attribute__((aligned(16))) char lx[LDSX_BYTES];
    const int tid  = threadIdx.x;
    const int wave = tid >> 6, lane = tid & 63;

    const unsigned int flat = blockIdx.x;           // 0..3999
    const int b = flat & 7;                         // XCD swizzle: batch per XCD
    const unsigned int l = flat >> 3;               // 0..499
    const int chunk = l % NCHM;
    const int hq    = l / NCHM;                     // 0..19
    const int h0 = hq * 4;
    const int w0 = chunk * 32;
    const int h   = h0 + (wave & 3);
    const int mtb = (wave >> 2) * 2;                // o-half: mt in {mtb, mtb+1}
    const int l15 = lane & 15, kq = lane >> 4;

    // ---- Fused stage: split-phase transpose+convert+swizzle ----
    {
        f32x4 v[2][8];
        int ok[2];
        unsigned int wb[2];
        int swz[2];
        // Phase A: compute addresses, issue all 16 loads
#pragma unroll
        for (int it = 0; it < 2; ++it) {
            const int T = tid + it * 512;
            ok[it] = 0;
            if (T < NTASK) {
                const int row = T % 10;
                const int q   = (T / 10) % 11;
                const int g   = T / 110;            // ch-group 0..7
                const int ca  = w0 - 4 + 4 * q;     // absolute col of quad
                if (ca >= 0 && ca + 3 < W_) {
                    ok[it] = 1;
                    int ar = h0 - 3 + row;
                    ar = ar < 0 ? 0 : (ar > H_ - 1 ? H_ - 1 : ar);
                    const float* s0 = x + ((size_t)(b * C_ + g * 8) * H_ + ar) * W_ + ca;
#pragma unroll
                    for (int c = 0; c < 8; ++c)
                        v[it][c] = *(const f32x4*)(s0 + (size_t)c * (H_ * W_));
                    wb[it]  = (unsigned int)row * ROWB_ + (unsigned int)(4 * q) * 128u;
                    swz[it] = g + ca;
                }
            }
        }
        // Phase B: pack + swizzled b128 writes
#pragma unroll
        for (int it = 0; it < 2; ++it) {
            if (ok[it]) {
#pragma unroll
                for (int i = 0; i < 4; ++i) {
                    unsigned int u[4];
#pragma unroll
                    for (int j = 0; j < 4; ++j)
                        u[j] = (unsigned int)f2bf(v[it][2 * j][i])
                             | ((unsigned int)f2bf(v[it][2 * j + 1][i]) << 16);
                    char* dst = lx + wb[it] + (unsigned int)(i * 128)
                              + (unsigned int)(((swz[it] + i) & 7) << 4);
                    *(uint4*)dst = make_uint4(u[0], u[1], u[2], u[3]);
                }
            }
        }
    }

    // ---- Per-pixel gather addresses (LDS byte offsets) ----
    // 25*32 == 800 exactly: pw < W_ always, no clamps needed.
    unsigned int rowb[2][3], colb[2][3];
#pragma unroll
    for (int nt = 0; nt < 2; ++nt) {
        const int pw  = w0 + nt * 16 + l15;
        const int dhi = (int)dh[b * W_ + pw];
        const int dwi = (int)dw[b * W_ + pw];
        int rD = h - dhi;   if (rD < 0) rD = -rD;
        const int rU = (h + dhi < H_) ? (h + dhi) : h;
        int cL = pw - dwi;  if (cL < 0) cL = -cL;
        const int cR = (pw + dwi < W_) ? (pw + dwi) : (2 * W_ - 1 - pw - dwi);
        rowb[nt][0] = (unsigned int)(rD - h0 + 3) * ROWB_;
        rowb[nt][1] = (unsigned int)(h  - h0 + 3) * ROWB_;
        rowb[nt][2] = (unsigned int)(rU - h0 + 3) * ROWB_;
        const int cs[3] = {cL, pw, cR};
#pragma unroll
        for (int j = 0; j < 3; ++j)
            colb[nt][j] = (unsigned int)(cs[j] - (w0 - 4)) * 128u
                        + (unsigned int)(((cs[j] + kq) & 7) * 16);
    }

    const char* wfb = (const char*)wfrag;
    const unsigned int aoff = (unsigned int)lane * 16u;

    // acc init = bias
    f32x4 acc[2][2];
#pragma unroll
    for (int mtl = 0; mtl < 2; ++mtl) {
        const f32x4 bv = *(const f32x4*)(bias + (mtb + mtl) * 16 + kq * 4);
#pragma unroll
        for (int nt = 0; nt < 2; ++nt)
#pragma unroll
            for (int r = 0; r < 4; ++r) acc[mtl][nt][r] = bv[r];
    }

    __syncthreads();   // staging complete

    // ---- K loop: 18 steps; B dist-1 (LDS), A dist-2 (global) prefetch ----
    bf16x8 bcur[2], bnxt[2], a0[2], a1[2], a2[2];
#pragma unroll
    for (int nt = 0; nt < 2; ++nt)
        bcur[nt] = *(const bf16x8*)(lx + rowb[nt][0] + colb[nt][0]);
#pragma unroll
    for (int mtl = 0; mtl < 2; ++mtl) {
        a0[mtl] = *(const bf16x8*)(wfb + (unsigned int)((0 * 4 + mtb + mtl) * 1024) + aoff);
        a1[mtl] = *(const bf16x8*)(wfb + (unsigned int)((1 * 4 + mtb + mtl) * 1024) + aoff);
    }

#pragma unroll
    for (int s = 0; s < 18; ++s) {
        if (s < 17) {
            const int sn = s + 1;
            const int tap = sn >> 1, hf = sn & 1;
            const int i = tap / 3, j = tap % 3;
#pragma unroll
            for (int nt = 0; nt < 2; ++nt) {
                // group+=4 rotation on colb ONLY (pre-rowb): pad-safe
                const unsigned int cb = colb[nt][j] ^ (hf ? 64u : 0u);
                bnxt[nt] = *(const bf16x8*)(lx + rowb[nt][i] + cb);
            }
        }
        if (s < 16) {
#pragma unroll
            for (int mtl = 0; mtl < 2; ++mtl)
                a2[mtl] = *(const bf16x8*)(wfb
                            + (unsigned int)(((s + 2) * 4 + mtb + mtl) * 1024) + aoff);
        }
#pragma unroll
        for (int mtl = 0; mtl < 2; ++mtl)
#pragma unroll
            for (int nt = 0; nt < 2; ++nt)
                acc[mtl][nt] = __builtin_amdgcn_mfma_f32_16x16x32_bf16(
                    a0[mtl], bcur[nt], acc[mtl][nt], 0, 0, 0);
#pragma unroll
        for (int nt = 0; nt < 2; ++nt) bcur[nt] = bnxt[nt];
#pragma unroll
        for (int mtl = 0; mtl < 2; ++mtl) { a0[mtl] = a1[mtl]; a1[mtl] = a2[mtl]; }
    }

    // ---- Epilogue: out[b][o][h][w] (w always < W_: exact chunking) ----
#pragma unroll
    for (int mtl = 0; mtl < 2; ++mtl) {
#pragma unroll
        for (int nt = 0; nt < 2; ++nt) {
            const int w = w0 + nt * 16 + l15;
            const unsigned int ob =
                ((unsigned int)(b * O_ + (mtb + mtl) * 16 + kq * 4) * (unsigned int)H_
                 + (unsigned int)h) * (unsigned int)W_ + (unsigned int)w;
#pragma unroll
            for (int r = 0; r < 4; ++r)
                out[ob + (unsigned int)r * 64000u] = acc[mtl][nt][r];
        }
    }
}

extern "C" void kernel_launch(void* const* d_in, const int* in_sizes, int n_in,
                              void* d_out, int out_size, void* d_ws, size_t ws_size,
                              hipStream_t stream) {
    const float* x      = (const float*)d_in[0];   // (8,64,80,800)
    const float* dh     = (const float*)d_in[1];   // (8,1,800)
    const float* dw     = (const float*)d_in[2];   // (8,1,800)
    const float* weight = (const float*)d_in[3];   // (9,64,64)
    const float* bias   = (const float*)d_in[4];   // (64,)
    float* out = (float*)d_out;

    unsigned short* wfrag = (unsigned short*)d_ws; // 73,728 B only

    k_wfrag<<<dim3(144), 256, 0, stream>>>(weight, wfrag);
    k_main<<<dim3(NCHM * (H_ / 4) * B_), 512, 0, stream>>>(x, wfrag, dh, dw, bias, out);
}

// Round 9
// 296.824 us; speedup vs baseline: 1.1076x; 1.1076x over previous
//
#include <hip/hip_runtime.h>

// Problem constants
#define B_  8
#define C_  64
#define O_  64
#define H_  80
#define W_  800
#define NCHM   25          // main kernel: 800/32 exact 32-px chunks

#define ROWS_  10          // staged halo rows: h0-3 .. h0+6 (4 output rows)
#define ROWPX_ 44          // staged cols w0-4 .. w0+39 (quad-aligned)
#define ROWB_  5648u       // 44*128 + 16 pad: rows rotate banksets (write spread)
#define LDSX_BYTES (ROWS_ * 5648)      // 56480 B -> 2 blocks/CU @ 512 thr
#define NTASK  880         // 10 rows * 8 ch-groups * 11 px-quads

typedef short bf16x8 __attribute__((ext_vector_type(8)));
typedef float f32x4  __attribute__((ext_vector_type(4)));

__device__ __forceinline__ unsigned short f2bf(float f) {
    unsigned int u = __float_as_uint(f);
    unsigned int r = u + 0x7FFFu + ((u >> 16) & 1u);   // RNE
    return (unsigned short)(r >> 16);
}

// ---------------------------------------------------------------------------
// Kernel 1: pre-swizzle weight (9,O,C) fp32 into exact A-fragment order, bf16.
// ---------------------------------------------------------------------------
__global__ void k_wfrag(const float* __restrict__ wt, unsigned short* __restrict__ wf) {
    const int t = blockIdx.x * 256 + threadIdx.x;   // < 36864
    const int j    = t & 7;
    const int lane = (t >> 3) & 63;
    const int mt   = (t >> 9) & 3;
    const int ks   = t >> 11;                       // 0..17
    const int tap  = ks >> 1, hf = ks & 1;
    const int o = mt * 16 + (lane & 15);
    const int c = hf * 32 + (lane >> 4) * 8 + j;
    wf[t] = f2bf(wt[(tap * 64 + o) * 64 + c]);
}

// ---------------------------------------------------------------------------
// Kernel 2: FUSED transpose + gather-GEMM, single pass over x.
// Block = 512 thr = 8 waves over (4 h rows) x (2 o-halves); 32-px chunk.
//
// Stage v4 (fixes round-8's two measured defects):
//  * task = (row, g, q) with q FASTEST across consecutive threads: 11-lane
//    runs read 176 contiguous bytes per channel (round 8's row-fastest order
//    gave adjacent lanes 3200-B-apart addresses -> FETCH 74 MB, BW 15%).
//  * phase A is BRANCH-FREE: T and ca are clamped (loads always valid),
//    validity only gates the phase-B writes. All 16 global float4 loads can
//    therefore batch into v[2][8] before the first use -> one latency
//    round-trip (round 4/8's guarded loads serialized; VGPR stuck at 52).
// Phase B (unchanged from PASSING round 8): pack RNE, one ds_write_b128 per
// pixel at lx[row*5648 + px*128 + ((g+ca+i)&7)*16]. ROWB=5648 rotates
// banksets per row (conflicts 11.9M->6.3M measured in round 8).
//
// Gather/K-loop: identical to round 8, including the pad-safe group rotation
// applied to colb BEFORE adding rowb (a = rowb + (colb ^ 64)).
// ---------------------------------------------------------------------------
__global__ void __launch_bounds__(512, 4)
k_main(const float* __restrict__ x,
       const unsigned short* __restrict__ wfrag,
       const float* __restrict__ dh, const float* __restrict__ dw,
       const float* __restrict__ bias, float* __restrict__ out) {
    __shared__ __attribute__((aligned(16))) char lx[LDSX_BYTES];
    const int tid  = threadIdx.x;
    const int wave = tid >> 6, lane = tid & 63;

    const unsigned int flat = blockIdx.x;           // 0..3999
    const int b = flat & 7;                         // XCD swizzle: batch per XCD
    const unsigned int l = flat >> 3;               // 0..499
    const int chunk = l % NCHM;
    const int hq    = l / NCHM;                     // 0..19
    const int h0 = hq * 4;
    const int w0 = chunk * 32;
    const int h   = h0 + (wave & 3);
    const int mtb = (wave >> 2) * 2;                // o-half: mt in {mtb, mtb+1}
    const int l15 = lane & 15, kq = lane >> 4;

    // ---- Fused stage v4: branch-free batched loads, then pack+write ----
    {
        f32x4 v[2][8];
        unsigned int wb[2];
        int swz[2], ok[2];
        // Phase A: clamped addresses, ALL 16 loads issued before any use
#pragma unroll
        for (int it = 0; it < 2; ++it) {
            const int T  = tid + it * 512;              // 0..1023
            const int Tc = T < NTASK ? T : NTASK - 1;   // clamp: safe addr
            const int row = Tc / 88;                    // 0..9
            const int rem = Tc - row * 88;
            const int g   = rem / 11;                   // ch-group 0..7
            const int q   = rem - g * 11;               // px-quad 0..10 (fastest)
            const int ca  = w0 - 4 + 4 * q;             // absolute col of quad
            const int cac = ca < 0 ? 0 : (ca > W_ - 4 ? W_ - 4 : ca);
            int ar = h0 - 3 + row;
            ar = ar < 0 ? 0 : (ar > H_ - 1 ? H_ - 1 : ar);
            const float* s0 = x + ((size_t)(b * C_ + g * 8) * H_ + ar) * W_ + cac;
#pragma unroll
            for (int c = 0; c < 8; ++c)
                v[it][c] = *(const f32x4*)(s0 + (size_t)c * (H_ * W_));
            wb[it]  = (unsigned int)row * ROWB_ + (unsigned int)(4 * q) * 128u;
            swz[it] = g + ca;
            ok[it]  = (T < NTASK) & (ca >= 0) & (ca + 3 < W_);
        }
        // Phase B: pack + swizzled b128 writes (validity-gated)
#pragma unroll
        for (int it = 0; it < 2; ++it) {
            if (ok[it]) {
#pragma unroll
                for (int i = 0; i < 4; ++i) {
                    unsigned int u[4];
#pragma unroll
                    for (int j = 0; j < 4; ++j)
                        u[j] = (unsigned int)f2bf(v[it][2 * j][i])
                             | ((unsigned int)f2bf(v[it][2 * j + 1][i]) << 16);
                    char* dst = lx + wb[it] + (unsigned int)(i * 128)
                              + (unsigned int)(((swz[it] + i) & 7) << 4);
                    *(uint4*)dst = make_uint4(u[0], u[1], u[2], u[3]);
                }
            }
        }
    }

    // ---- Per-pixel gather addresses (LDS byte offsets) ----
    // 25*32 == 800 exactly: pw < W_ always, no clamps needed.
    unsigned int rowb[2][3], colb[2][3];
#pragma unroll
    for (int nt = 0; nt < 2; ++nt) {
        const int pw  = w0 + nt * 16 + l15;
        const int dhi = (int)dh[b * W_ + pw];
        const int dwi = (int)dw[b * W_ + pw];
        int rD = h - dhi;   if (rD < 0) rD = -rD;
        const int rU = (h + dhi < H_) ? (h + dhi) : h;
        int cL = pw - dwi;  if (cL < 0) cL = -cL;
        const int cR = (pw + dwi < W_) ? (pw + dwi) : (2 * W_ - 1 - pw - dwi);
        rowb[nt][0] = (unsigned int)(rD - h0 + 3) * ROWB_;
        rowb[nt][1] = (unsigned int)(h  - h0 + 3) * ROWB_;
        rowb[nt][2] = (unsigned int)(rU - h0 + 3) * ROWB_;
        const int cs[3] = {cL, pw, cR};
#pragma unroll
        for (int j = 0; j < 3; ++j)
            colb[nt][j] = (unsigned int)(cs[j] - (w0 - 4)) * 128u
                        + (unsigned int)(((cs[j] + kq) & 7) * 16);
    }

    const char* wfb = (const char*)wfrag;
    const unsigned int aoff = (unsigned int)lane * 16u;

    // acc init = bias
    f32x4 acc[2][2];
#pragma unroll
    for (int mtl = 0; mtl < 2; ++mtl) {
        const f32x4 bv = *(const f32x4*)(bias + (mtb + mtl) * 16 + kq * 4);
#pragma unroll
        for (int nt = 0; nt < 2; ++nt)
#pragma unroll
            for (int r = 0; r < 4; ++r) acc[mtl][nt][r] = bv[r];
    }

    __syncthreads();   // staging complete

    // ---- K loop: 18 steps; B dist-1 (LDS), A dist-2 (global) prefetch ----
    bf16x8 bcur[2], bnxt[2], a0[2], a1[2], a2[2];
#pragma unroll
    for (int nt = 0; nt < 2; ++nt)
        bcur[nt] = *(const bf16x8*)(lx + rowb[nt][0] + colb[nt][0]);
#pragma unroll
    for (int mtl = 0; mtl < 2; ++mtl) {
        a0[mtl] = *(const bf16x8*)(wfb + (unsigned int)((0 * 4 + mtb + mtl) * 1024) + aoff);
        a1[mtl] = *(const bf16x8*)(wfb + (unsigned int)((1 * 4 + mtb + mtl) * 1024) + aoff);
    }

#pragma unroll
    for (int s = 0; s < 18; ++s) {
        if (s < 17) {
            const int sn = s + 1;
            const int tap = sn >> 1, hf = sn & 1;
            const int i = tap / 3, j = tap % 3;
#pragma unroll
            for (int nt = 0; nt < 2; ++nt) {
                // group+=4 rotation on colb ONLY (pre-rowb): pad-safe
                const unsigned int cb = colb[nt][j] ^ (hf ? 64u : 0u);
                bnxt[nt] = *(const bf16x8*)(lx + rowb[nt][i] + cb);
            }
        }
        if (s < 16) {
#pragma unroll
            for (int mtl = 0; mtl < 2; ++mtl)
                a2[mtl] = *(const bf16x8*)(wfb
                            + (unsigned int)(((s + 2) * 4 + mtb + mtl) * 1024) + aoff);
        }
#pragma unroll
        for (int mtl = 0; mtl < 2; ++mtl)
#pragma unroll
            for (int nt = 0; nt < 2; ++nt)
                acc[mtl][nt] = __builtin_amdgcn_mfma_f32_16x16x32_bf16(
                    a0[mtl], bcur[nt], acc[mtl][nt], 0, 0, 0);
#pragma unroll
        for (int nt = 0; nt < 2; ++nt) bcur[nt] = bnxt[nt];
#pragma unroll
        for (int mtl = 0; mtl < 2; ++mtl) { a0[mtl] = a1[mtl]; a1[mtl] = a2[mtl]; }
    }

    // ---- Epilogue: out[b][o][h][w] (w always < W_: exact chunking) ----
#pragma unroll
    for (int mtl = 0; mtl < 2; ++mtl) {
#pragma unroll
        for (int nt = 0; nt < 2; ++nt) {
            const int w = w0 + nt * 16 + l15;
            const unsigned int ob =
                ((unsigned int)(b * O_ + (mtb + mtl) * 16 + kq * 4) * (unsigned int)H_
                 + (unsigned int)h) * (unsigned int)W_ + (unsigned int)w;
#pragma unroll
            for (int r = 0; r < 4; ++r)
                out[ob + (unsigned int)r * 64000u] = acc[mtl][nt][r];
        }
    }
}

extern "C" void kernel_launch(void* const* d_in, const int* in_sizes, int n_in,
                              void* d_out, int out_size, void* d_ws, size_t ws_size,
                              hipStream_t stream) {
    const float* x      = (const float*)d_in[0];   // (8,64,80,800)
    const float* dh     = (const float*)d_in[1];   // (8,1,800)
    const float* dw     = (const float*)d_in[2];   // (8,1,800)
    const float* weight = (const float*)d_in[3];   // (9,64,64)
    const float* bias   = (const float*)d_in[4];   // (64,)
    float* out = (float*)d_out;

    unsigned short* wfrag = (unsigned short*)d_ws; // 73,728 B only

    k_wfrag<<<dim3(144), 256, 0, stream>>>(weight, wfrag);
    k_main<<<dim3(NCHM * (H_ / 4) * B_), 512, 0, stream>>>(x, wfrag, dh, dw, bias, out);
}